// Round 17
// baseline (375.595 us; speedup 1.0000x reference)
//
#include <hip/hip_runtime.h>
#include <stdint.h>

#define EFFECT_DIM 758
#define ADD_DIM 10
#define EMBED_DIM 768
#define NCOLS 95000
#define NSYN 8
#define NROWS 1024
#define NT256 372            // ceil(95000/256)
#define TILE_B 32768         // 256x64 bf16 A tile, fragment-ordered

typedef __attribute__((ext_vector_type(8))) __bf16 bf16x8;
typedef __attribute__((ext_vector_type(16))) float f32x16;
typedef __attribute__((ext_vector_type(4))) uint32_t u32x4;

// Fragment order: tile = [kk 0..3][grp 0..7][lane 0..63] x 16B.
// frag(kk,grp) = 1KB; lane = (row&31) + (khalf8<<5); 16B = 8 consecutive k.
// ds_read_b128 on this layout: 0 bank conflicts (measured R10-R16).

static __device__ __forceinline__ uint32_t pack2(float a, float b) {
  uint32_t r;
  asm("v_cvt_pk_bf16_f32 %0, %1, %2" : "=v"(r) : "v"(a), "v"(b));
  return r;
}

#define GLOAD16(src, dst)                                                   \
  __builtin_amdgcn_global_load_lds(                                         \
      (const __attribute__((address_space(1))) uint32_t*)(src),             \
      (__attribute__((address_space(3))) uint32_t*)(dst), 16, 0, 0)

#define F4C(f, i) ((i) == 0 ? (f).x : (i) == 1 ? (f).y : (i) == 2 ? (f).z : (f).w)

// ---------------------------------------------------------------------------
// Kernel 1: VirtualEmbedding -> bf16 A tiles (4 m-tiles x 12 ks), frag order.
// (verified R9-R16)
// ---------------------------------------------------------------------------
__global__ __launch_bounds__(256) void emb_kernel(
    const int* __restrict__ ids, const float* __restrict__ W_emb,
    const float* __restrict__ padding, const int* __restrict__ syn_table,
    const int* __restrict__ syn_mask, char* __restrict__ ws)
{
  const int l = blockIdx.x;
  const int t = threadIdx.x;
  const int id = ids[l];
  int sid[NSYN];
  int msk[NSYN];
#pragma unroll
  for (int k = 0; k < NSYN; ++k) {
    sid[k] = syn_table[id * NSYN + k];
    msk[k] = syn_mask[id * NSYN + k];
  }

  double p[9] = {0, 0, 0, 0, 0, 0, 0, 0, 0};
  for (int d = t; d < EFFECT_DIM; d += 256) {
    p[0] += (double)W_emb[(size_t)id * EFFECT_DIM + d];
#pragma unroll
    for (int k = 0; k < NSYN; ++k)
      p[k + 1] += (double)W_emb[(size_t)sid[k] * EFFECT_DIM + d];
  }

  __shared__ double s_red[9][4];
  const int w = t >> 6;
#pragma unroll
  for (int k = 0; k < 9; ++k) {
    double v = p[k];
#pragma unroll
    for (int off = 32; off > 0; off >>= 1) v += __shfl_down(v, off, 64);
    if ((t & 63) == 0) s_red[k][w] = v;
  }
  __syncthreads();

  const double isum = s_red[0][0] + s_red[0][1] + s_red[0][2] + s_red[0][3];
  float coef[NSYN];
#pragma unroll
  for (int k = 0; k < NSYN; ++k) {
    double ss = s_red[k + 1][0] + s_red[k + 1][1] + s_red[k + 1][2] + s_red[k + 1][3];
    coef[k] = msk[k] ? (float)(isum / ss) : 0.0f;
  }

  const int r = l & 255;
  char* wbase = ws + (size_t)(l >> 8) * (12 * TILE_B);

  for (int j = t; j < 384; j += 256) {
    const int d0 = 2 * j;
    float v0, v1;
    if (d0 < EFFECT_DIM) {
      const float* bp = W_emb + (size_t)id * EFFECT_DIM + d0;
      v0 = bp[0];
      v1 = bp[1];
#pragma unroll
      for (int k = 0; k < NSYN; ++k) {
        const float* sp = W_emb + (size_t)sid[k] * EFFECT_DIM + d0;
        v0 = fmaf(coef[k], sp[0], v0);
        v1 = fmaf(coef[k], sp[1], v1);
      }
    } else {
      v0 = padding[l * ADD_DIM + (d0 - EFFECT_DIM)];
      v1 = padding[l * ADD_DIM + (d0 + 1 - EFFECT_DIM)];
    }
    const int ks   = j >> 5;
    const int jl   = j & 31;
    const int kk   = jl >> 3;
    const int byte = (jl & 7) * 4;
    const int lane = (r & 31) + ((byte >> 4) << 5);
    *(uint32_t*)(wbase + ks * TILE_B + kk * 8192 + (r >> 5) * 1024 +
                 lane * 16 + (byte & 15)) = pack2(v0, v1);
  }
}

// ---------------------------------------------------------------------------
// Kernel 2 (R17 = R16 + float4 B loads + NT epilogue): 256x256 tile,
// 512 thr, 8 waves (2m x 4n), wave 128x64, acc[4][2]. LDS 128KB = 2 sets x
// [A 32K][B 32K], frag-ordered. Per K-step T (computing set cs = T&1):
//   AGLD(cs^1, T+1)          // 4 gload_lds, OLDEST in vm queue
//   BLOAD(brNext, T+2)       // 8 x global_load_dwordx4 (4n x 8k/thread)
//   4 x {6 ds_read_b128 + 8 MFMA (setprio)}
//   BSTORE(brCur = B(T+1))   // loaded a FULL step ago -> retired
//   lgkmcnt(0); vmcnt(8)     // A(T+1) confirmed, B(T+2)'s 8 stay in flight
//   s_barrier
// Epilogue uses nontemporal stores (write-once out; protect L2 B panels).
// T1 remap 1488 = 8 x 186: 4 mt-siblings share W_rev panel per XCD.
// ---------------------------------------------------------------------------
__global__ __launch_bounds__(512, 2) void gemm_fused(
    const float* __restrict__ Wrev, const char* __restrict__ Abuf,
    float* __restrict__ out)
{
  extern __shared__ char lds[];  // set s at s*65536: [A 32K][B 32K]
  const int t = threadIdx.x;
  const int l = t & 63;
  const int w = t >> 6;
  const int wm = w >> 2;       // 0..1
  const int wn = w & 3;        // 0..3

  const int wgid = blockIdx.x;            // 1488 = 8 x 186
  const int xcd  = wgid & 7;
  const int work = xcd * 186 + (wgid >> 3);
  const int mt = work & 3;
  const int nt = work >> 2;
  const int n0 = nt * 256;

  const char* asrc = Abuf + (size_t)mt * (12 * TILE_B);

  // B staging role: thread owns 4 consecutive n (sn4*4..+3), 8 k (kg*8..+7)
  const int sn4 = t & 63;      // n-quad index within 256
  const int kg  = t >> 6;      // 0..7
  const int gn4 = n0 + sn4 * 4;
  const bool valid = (gn4 + 4) <= NCOLS;   // NCOLS % 4 == 0
  const int kk_s = kg >> 1;    // dest kk block
  const int kh_s = kg & 1;     // dest k-half within 16B frag rows

  float4 br0[8], br1[8];

#define AGLD(s, ksi)                                                         \
  {                                                                          \
    _Pragma("unroll") for (int kk = 0; kk < 4; ++kk)                         \
      GLOAD16(asrc + (ksi)*TILE_B + kk*8192 + t*16,                          \
              lds + (s)*65536 + kk*8192 + w*1024);                           \
  }

#define BLOAD(br, ksi)                                                       \
  {                                                                          \
    const float* p = Wrev + (size_t)((ksi)*64 + kg*8) * NCOLS + gn4;         \
    _Pragma("unroll") for (int j = 0; j < 8; ++j)                            \
      br[j] = valid ? *(const float4*)(p + (size_t)j * NCOLS)                \
                    : float4{0.0f, 0.0f, 0.0f, 0.0f};                        \
  }

#define BSTORE(br, s)                                                        \
  {                                                                          \
    _Pragma("unroll") for (int i = 0; i < 4; ++i) {                          \
      const int n = sn4 * 4 + i;                                             \
      u32x4 u;                                                               \
      _Pragma("unroll") for (int jj = 0; jj < 4; ++jj)                       \
        u[jj] = pack2(F4C(br[2*jj], i), F4C(br[2*jj + 1], i));               \
      *(u32x4*)(lds + (s)*65536 + 32768 + kk_s*8192 + (n >> 5)*1024 +        \
                ((n & 31) + (kh_s << 5)) * 16) = u;                          \
    }                                                                        \
  }

#define COMPUTE(cs)                                                          \
  {                                                                          \
    const char* aw = lds + (cs)*65536 + (wm*4)*1024 + l*16;                  \
    const char* bw = lds + (cs)*65536 + 32768 + (wn*2)*1024 + l*16;          \
    _Pragma("unroll") for (int p = 0; p < 4; ++p) {                          \
      bf16x8 a[4], b[2];                                                     \
      _Pragma("unroll") for (int mr = 0; mr < 4; ++mr)                       \
        a[mr] = *(const bf16x8*)(aw + p*8192 + mr*1024);                     \
      _Pragma("unroll") for (int nr = 0; nr < 2; ++nr)                       \
        b[nr] = *(const bf16x8*)(bw + p*8192 + nr*1024);                     \
      __builtin_amdgcn_s_setprio(1);                                         \
      _Pragma("unroll") for (int mr = 0; mr < 4; ++mr)                       \
        _Pragma("unroll") for (int nr = 0; nr < 2; ++nr)                     \
          acc[mr][nr] = __builtin_amdgcn_mfma_f32_32x32x16_bf16(             \
              a[mr], b[nr], acc[mr][nr], 0, 0, 0);                           \
      __builtin_amdgcn_s_setprio(0);                                         \
    }                                                                        \
  }

#define STEP(cs, TT, brCur, brNext)                                          \
  {                                                                          \
    if ((TT) + 1 < 12) AGLD((cs) ^ 1, (TT) + 1);       /* oldest in queue */ \
    if ((TT) + 2 < 12) BLOAD(brNext, (TT) + 2);                              \
    __builtin_amdgcn_sched_barrier(0);                                       \
    COMPUTE(cs);                                                             \
    __builtin_amdgcn_sched_barrier(0);                                       \
    if ((TT) + 1 < 12) {                                                     \
      BSTORE(brCur, (cs) ^ 1);         /* brCur loaded a full step ago */    \
      asm volatile("s_waitcnt lgkmcnt(0)" ::: "memory");                     \
      if ((TT) + 2 < 12) asm volatile("s_waitcnt vmcnt(8)" ::: "memory");    \
      else               asm volatile("s_waitcnt vmcnt(0)" ::: "memory");    \
      __builtin_amdgcn_sched_barrier(0);                                     \
      __builtin_amdgcn_s_barrier();                                          \
    }                                                                        \
  }

  // prologue: tile 0 -> set 0; preload B(1) into br0
  AGLD(0, 0);
  BLOAD(br0, 0);
  BSTORE(br0, 0);   // compiler waits br0 (drains A(0) too — older)
  BLOAD(br0, 1);
  asm volatile("s_waitcnt lgkmcnt(0)" ::: "memory");
  __builtin_amdgcn_sched_barrier(0);
  __builtin_amdgcn_s_barrier();

  f32x16 acc[4][2] = {};

#pragma unroll
  for (int Ti = 0; Ti < 6; ++Ti) {
    STEP(0, 2 * Ti,     br0, br1);
    STEP(1, 2 * Ti + 1, br1, br0);
  }
#undef STEP
#undef COMPUTE
#undef AGLD
#undef BLOAD
#undef BSTORE

  // epilogue (nontemporal): col=lane&31, row=(reg&3)+8*(reg>>2)+4*(lane>>5)
  const int lh = l >> 5;
#pragma unroll
  for (int nr = 0; nr < 2; ++nr) {
    const int gc = n0 + wn * 64 + nr * 32 + (l & 31);
    if (gc < NCOLS) {
#pragma unroll
      for (int mr = 0; mr < 4; ++mr)
#pragma unroll
        for (int reg = 0; reg < 16; ++reg) {
          const int row = mt * 256 + wm * 128 + mr * 32 +
                          (reg & 3) + 8 * (reg >> 2) + 4 * lh;
          __builtin_nontemporal_store(acc[mr][nr][reg],
                                      &out[(size_t)row * NCOLS + gc]);
        }
    }
  }
}

extern "C" void kernel_launch(void* const* d_in, const int* in_sizes, int n_in,
                              void* d_out, int out_size, void* d_ws, size_t ws_size,
                              hipStream_t stream) {
  const int*   ids       = (const int*)d_in[0];
  const float* W_emb     = (const float*)d_in[1];
  const float* W_rev     = (const float*)d_in[2];
  const float* padding   = (const float*)d_in[3];
  const int*   syn_table = (const int*)d_in[4];
  const int*   syn_mask  = (const int*)d_in[5];
  float* out = (float*)d_out;
  char*  ws  = (char*)d_ws;

  // A tiles in ws[0, 1.5MB); conv pass deleted
  hipLaunchKernelGGL(emb_kernel, dim3(NROWS), dim3(256), 0, stream,
                     ids, W_emb, padding, syn_table, syn_mask, ws);

  // 1488 blocks: 4 m-tiles x 372 n-tiles = 8 XCDs x 186 (bijective)
  hipLaunchKernelGGL(gemm_fused, dim3(4 * NT256), dim3(512), 131072, stream,
                     W_rev, ws, out);
}